// Round 6
// baseline (1228.203 us; speedup 1.0000x reference)
//
#include <hip/hip_runtime.h>
#include <hip/hip_bf16.h>

#define B_    8192
#define D_    2048
#define H_    4096
#define C_    64
#define HALF_ 1024
#define KIN_  1088   // HALF_ + C_

typedef __attribute__((ext_vector_type(8))) short bf16x8;
typedef __attribute__((ext_vector_type(16))) float f32x16;

__device__ __forceinline__ unsigned short f2bf(float f) {
  __hip_bfloat16 h = __float2bfloat16(f);
  return *reinterpret_cast<unsigned short*>(&h);
}

__device__ __forceinline__ void gload16(const void* g, void* s) {
  __builtin_amdgcn_global_load_lds((const __attribute__((address_space(1))) void*)g,
                                   (__attribute__((address_space(3))) void*)s,
                                   16, 0, 0);
}

// W [K,N] fp32 row-major  ->  Wt [N,K] bf16 row-major (transpose + convert)
__global__ void convT(const float* __restrict__ W, unsigned short* __restrict__ Wt,
                      int K, int N) {
  __shared__ float tile[32][33];
  int tx = threadIdx.x & 31, ty = threadIdx.x >> 5;   // 32x8 threads
  int n0 = blockIdx.x * 32, k0 = blockIdx.y * 32;
#pragma unroll
  for (int i = 0; i < 4; ++i)
    tile[ty + i * 8][tx] = W[(size_t)(k0 + ty + i * 8) * N + n0 + tx];
  __syncthreads();
#pragma unroll
  for (int i = 0; i < 4; ++i)
    Wt[(size_t)(n0 + ty + i * 8) * K + k0 + tx] = f2bf(tile[tx][ty + i * 8]);
}

// A0[b, c<1024] = xsrc[b, 2c+par], A0[b, 1024:1088] = condition[b, .]  (bf16)
__global__ void build_act(const float* __restrict__ xsrc, const float* __restrict__ cond,
                          int par, unsigned short* __restrict__ A0) {
  int row = blockIdx.y;
  int col = blockIdx.x * 256 + threadIdx.x;
  if (col >= KIN_) return;
  float v;
  if (col < HALF_) {
    float2 p = ((const float2*)xsrc)[(size_t)row * (D_ / 2) + col];
    v = par ? p.y : p.x;
  } else {
    v = cond[(size_t)row * C_ + (col - HALF_)];
  }
  A0[(size_t)row * KIN_ + col] = f2bf(v);
}

// ---------------------------------------------------------------------------
// 8-phase 256x256 GEMM, BK=64, 8 waves (2Mx4N), 2-buffer 128 KiB LDS, counted
// vmcnt(6) — schedule/ledger identical to R3/R4 (verified). MFMA 32x32x16.
//
// LDS layout (per 64KB buffer): A [4 kk4][8 mb][1024B] @ +0, B same @ +32768.
// Group (kk4, rb) = 32 rows x 16 k = 8 lines of 128B. Cell (r in 0..31,
// h in 0..1) -> line t = (r&15)>>1, logical cb = ((r&1)<<2)|(h<<1)|(r>>4),
// PHYS chunk = cb ^ t. This makes every ds_read_b128 (frag m|n, kk4) have
// QW q covering the SAME 8-line window with chunks {q,q+4}^t — bit-identical
// to the R3/R4 pattern measured at 0 bank conflicts (64-bank parity model:
// each chunk-group's 4 lanes split 2+2 across line parities = free 2-way).
// Staging: linear LDS dest + inverse-swizzled per-lane GLOBAL source.
// MODE 0: C = bf16(relu(.+bias)) via R4's verbatim measured-0 LDS bounce.
// MODE 1: fused coupling epilogue (S,T cols; scatter x-update + S partials).
// ---------------------------------------------------------------------------
template <int MODE>
__global__ __launch_bounds__(512, 2)
void gemm8p(const unsigned short* __restrict__ A,
            const unsigned short* __restrict__ Bt,
            const float* __restrict__ bias,
            unsigned short* __restrict__ Cout,
            const float* __restrict__ xold, float* __restrict__ xnew,
            float* __restrict__ part, int par,
            int M, int N, int K) {
  __shared__ unsigned short lds[65536];   // 128 KiB
  char* ldsb = (char*)lds;
  const int tid = threadIdx.x;
  const int w = tid >> 6, lane = tid & 63;
  const int l31 = lane & 31, hi = lane >> 5;
  const int wr = w >> 2, wc = w & 3;          // 2x4 waves, wave tile 128x64

  // XCD-aware block swizzle (nwg % 8 == 0 for all our grids)
  const int nbx = N >> 8;
  const int nwg = (int)gridDim.x;
  const int cpx = nwg >> 3;
  const int bid = (int)blockIdx.x;
  const int swz = (bid & 7) * cpx + (bid >> 3);
  const int by = swz / nbx, bx = swz - by * nbx;
  const int m0 = by << 8, n0 = bx << 8;

  // read-side: common within-group offset (same formula for A and B)
  const int t = (l31 & 15) >> 1;
  const int cbr = ((l31 & 1) << 2) | (hi << 1) | (l31 >> 4);
  const int rdoff = t * 128 + ((cbr ^ t) << 4);
  // A frag (m, kk4): bufC + kk4*8192 + (wr*4+m)*1024 + rdoff
  // B frag (n, kk4): bufC + 32768 + kk4*8192 + (wc*2+n)*1024 + rdoff
  const int Ab = (wr * 4) * 1024 + rdoff;
  const int Bb = 32768 + (wc * 2) * 1024 + rdoff;

  // stage-side: per-slot inverse-swizzled global source; linear LDS dest
  int rowS[2], kcolS[2];
  {
    const int ts = lane >> 3;
    const int cb = (lane & 7) ^ ts;
    const int rloc = ((cb & 1) << 4) + 2 * ts + ((cb >> 2) & 1);
    const int h = (cb >> 1) & 1;
#pragma unroll
    for (int s = 0; s < 2; ++s) {
      int gl = w * 2 + s;                 // group within 16KB unit
      rowS[s] = (gl & 7) * 32 + rloc;     // mb*32 + rloc
      kcolS[s] = (gl >> 3) * 16 + h * 8;  // kk4_local*16 + h*8
    }
  }
  const unsigned short* sA0 = A + (size_t)(m0 + rowS[0]) * K + kcolS[0];
  const unsigned short* sA1 = A + (size_t)(m0 + rowS[1]) * K + kcolS[1];
  const unsigned short* sB0 = Bt + (size_t)(n0 + rowS[0]) * K + kcolS[0];
  const unsigned short* sB1 = Bt + (size_t)(n0 + rowS[1]) * K + kcolS[1];
  const int dst0 = (w * 2) * 1024 + lane * 16;   // slot 0 byte offset in unit

#define STAGE_A(KK, TILE, BUF) do {                                          \
    gload16(sA0 + (TILE) * 64 + (KK) * 32,                                   \
            ldsb + (BUF) + (KK) * 16384 + dst0);                             \
    gload16(sA1 + (TILE) * 64 + (KK) * 32,                                   \
            ldsb + (BUF) + (KK) * 16384 + dst0 + 1024);                      \
  } while (0)
#define STAGE_B(KK, TILE, BUF) do {                                          \
    gload16(sB0 + (TILE) * 64 + (KK) * 32,                                   \
            ldsb + (BUF) + 32768 + (KK) * 16384 + dst0);                     \
    gload16(sB1 + (TILE) * 64 + (KK) * 32,                                   \
            ldsb + (BUF) + 32768 + (KK) * 16384 + dst0 + 1024);              \
  } while (0)

  f32x16 acc[4][2];
#pragma unroll
  for (int m = 0; m < 4; ++m)
#pragma unroll
    for (int n = 0; n < 2; ++n)
#pragma unroll
      for (int r = 0; r < 16; ++r) acc[m][n][r] = 0.f;

  const int NT = K >> 6;   // BK=64; K multiple of 64, NT >= 3

  // prologue: tile 0 (4 units) -> buf0; tile 1 first 3 units -> buf1
  STAGE_A(0, 0, 0);
  STAGE_A(1, 0, 0);
  STAGE_B(0, 0, 0);
  STAGE_B(1, 0, 0);
  STAGE_B(0, 1, 65536);
  STAGE_A(0, 1, 65536);
  STAGE_B(1, 1, 65536);
  asm volatile("s_waitcnt vmcnt(6)" ::: "memory");   // tile 0 landed
  __builtin_amdgcn_sched_barrier(0);
  __builtin_amdgcn_s_barrier();

#define PHASE_TAIL()                                                         \
    __builtin_amdgcn_sched_barrier(0);                                       \
    __builtin_amdgcn_s_barrier();                                            \
    asm volatile("s_waitcnt lgkmcnt(0)" ::: "memory");                       \
    __builtin_amdgcn_sched_barrier(0);

#define MFMA8(MB)                                                            \
    __builtin_amdgcn_s_setprio(1);                                           \
    _Pragma("unroll") for (int kk = 0; kk < 2; ++kk)                         \
      _Pragma("unroll") for (int mm = 0; mm < 2; ++mm)                       \
        _Pragma("unroll") for (int nn = 0; nn < 2; ++nn)                     \
          acc[(MB) + mm][nn] = __builtin_amdgcn_mfma_f32_32x32x16_bf16(      \
              av[mm][kk], bv[nn][kk], acc[(MB) + mm][nn], 0, 0, 0);          \
    __builtin_amdgcn_s_setprio(0);                                           \
    __builtin_amdgcn_sched_barrier(0);                                       \
    __builtin_amdgcn_s_barrier();

#define TILE32(TT, S1, S234, DO_VM)                                          \
  {                                                                          \
    const int bufC = ((TT) & 1) * 65536;                                     \
    const int bufN = 65536 - bufC;                                           \
    bf16x8 av[2][2], bv[2][2];                                               \
    /* ---- phase 1: kk4 0-1, m0-1, read B kk4 0-1 ---- */                   \
    _Pragma("unroll") for (int mm = 0; mm < 2; ++mm)                         \
      _Pragma("unroll") for (int kk = 0; kk < 2; ++kk)                       \
        av[mm][kk] = *(const bf16x8*)(ldsb + bufC + kk * 8192 + Ab + mm * 1024); \
    _Pragma("unroll") for (int nn = 0; nn < 2; ++nn)                         \
      _Pragma("unroll") for (int kk = 0; kk < 2; ++kk)                       \
        bv[nn][kk] = *(const bf16x8*)(ldsb + bufC + kk * 8192 + Bb + nn * 1024); \
    if (S1) { STAGE_A(1, (TT) + 1, bufN); }                                  \
    PHASE_TAIL()                                                             \
    MFMA8(0)                                                                 \
    /* ---- phase 2: kk4 0-1, m2-3 (B reused) ---- */                        \
    _Pragma("unroll") for (int mm = 0; mm < 2; ++mm)                         \
      _Pragma("unroll") for (int kk = 0; kk < 2; ++kk)                       \
        av[mm][kk] = *(const bf16x8*)(ldsb + bufC + kk * 8192 + Ab + (mm + 2) * 1024); \
    if (S234) { STAGE_B(0, (TT) + 2, bufC); }                                \
    PHASE_TAIL()                                                             \
    MFMA8(2)                                                                 \
    /* ---- phase 3: kk4 2-3, m0-1, read B kk4 2-3 ---- */                   \
    _Pragma("unroll") for (int mm = 0; mm < 2; ++mm)                         \
      _Pragma("unroll") for (int kk = 0; kk < 2; ++kk)                       \
        av[mm][kk] = *(const bf16x8*)(ldsb + bufC + (kk + 2) * 8192 + Ab + mm * 1024); \
    _Pragma("unroll") for (int nn = 0; nn < 2; ++nn)                         \
      _Pragma("unroll") for (int kk = 0; kk < 2; ++kk)                       \
        bv[nn][kk] = *(const bf16x8*)(ldsb + bufC + (kk + 2) * 8192 + Bb + nn * 1024); \
    if (S234) { STAGE_A(0, (TT) + 2, bufC); }                                \
    PHASE_TAIL()                                                             \
    MFMA8(0)                                                                 \
    /* ---- phase 4: kk4 2-3, m2-3 ---- */                                   \
    _Pragma("unroll") for (int mm = 0; mm < 2; ++mm)                         \
      _Pragma("unroll") for (int kk = 0; kk < 2; ++kk)                       \
        av[mm][kk] = *(const bf16x8*)(ldsb + bufC + (kk + 2) * 8192 + Ab + (mm + 2) * 1024); \
    if (S234) { STAGE_B(1, (TT) + 2, bufC); }                                \
    __builtin_amdgcn_sched_barrier(0);                                       \
    __builtin_amdgcn_s_barrier();                                            \
    asm volatile("s_waitcnt lgkmcnt(0)" ::: "memory");                       \
    __builtin_amdgcn_sched_barrier(0);                                       \
    __builtin_amdgcn_s_setprio(1);                                           \
    _Pragma("unroll") for (int kk = 0; kk < 2; ++kk)                         \
      _Pragma("unroll") for (int mm = 0; mm < 2; ++mm)                       \
        _Pragma("unroll") for (int nn = 0; nn < 2; ++nn)                     \
          acc[mm + 2][nn] = __builtin_amdgcn_mfma_f32_32x32x16_bf16(         \
              av[mm][kk], bv[nn][kk], acc[mm + 2][nn], 0, 0, 0);             \
    __builtin_amdgcn_s_setprio(0);                                           \
    __builtin_amdgcn_sched_barrier(0);                                       \
    if (DO_VM == 1) asm volatile("s_waitcnt vmcnt(6)" ::: "memory");         \
    if (DO_VM == 2) asm volatile("s_waitcnt vmcnt(0)" ::: "memory");         \
    __builtin_amdgcn_sched_barrier(0);                                       \
    __builtin_amdgcn_s_barrier();                                            \
  }

  for (int T = 0; T < NT - 2; ++T) {
    TILE32(T, 1, 1, 1)
  }
  TILE32(NT - 2, 1, 0, 2)
  TILE32(NT - 1, 0, 0, 0)
#undef TILE32
#undef MFMA8
#undef PHASE_TAIL
#undef STAGE_A
#undef STAGE_B

  // ---- epilogue ---- 32x32 C/D (m74/m101): col = l31, row = (r&3)+8*(r>>2)+4*hi
  if (MODE == 0) {
    // R4's verbatim measured-0 involution: phys32B = logical32B ^ ((lrow>>2)&3)
#pragma unroll
    for (int n = 0; n < 2; ++n) {
      float bb = bias[n0 + wc * 64 + n * 32 + l31];
#pragma unroll
      for (int m = 0; m < 4; ++m)
#pragma unroll
        for (int r = 0; r < 16; ++r) {
          float v = fmaxf(acc[m][n][r] + bb, 0.f);
          int lrow = m * 32 + (r & 3) + 8 * (r >> 2) + 4 * hi;
          int phys = (n * 2 + (l31 >> 4)) ^ ((lrow >> 2) & 3);
          *(unsigned short*)(ldsb + w * 16384 + lrow * 128 + phys * 32 + (l31 & 15) * 2) = f2bf(v);
        }
    }
    asm volatile("s_waitcnt lgkmcnt(0)" ::: "memory");   // own-wave region only
    __builtin_amdgcn_sched_barrier(0);
    unsigned short* Cb = Cout + (size_t)(m0 + wr * 128) * N + n0 + wc * 64;
    const int sub = lane & 7;
#pragma unroll
    for (int i = 0; i < 16; ++i) {
      int lrow = i * 8 + (lane >> 3);
      int phys = (sub >> 1) ^ ((lrow >> 2) & 3);
      bf16x8 val = *(const bf16x8*)(ldsb + w * 16384 + lrow * 128 + phys * 32 + (sub & 1) * 16);
      *(bf16x8*)(Cb + (size_t)lrow * N + sub * 8) = val;
    }
  } else {
    // fused coupling: even col = S, odd = T (pair via shfl_xor 1);
    // xnew[row][2j+par] = xold[row][2j+par]*exp(S)+T; S partials -> part.
#pragma unroll
    for (int m = 0; m < 4; ++m) {
      float sr[16];
#pragma unroll
      for (int r = 0; r < 16; ++r) sr[r] = 0.f;
#pragma unroll
      for (int n = 0; n < 2; ++n) {
        int gcol = n0 + wc * 64 + n * 32 + l31;
        float bb = bias[gcol];
#pragma unroll
        for (int r = 0; r < 16; ++r) {
          float v = acc[m][n][r] + bb;
          float vp = __shfl_xor(v, 1);
          if (!(lane & 1)) {
            int grow = m0 + wr * 128 + m * 32 + (r & 3) + 8 * (r >> 2) + 4 * hi;
            size_t idx = (size_t)grow * N + gcol + par;
            xnew[idx] = xold[idx] * expf(v) + vp;
            sr[r] += v;
          }
        }
      }
#pragma unroll
      for (int r = 0; r < 16; ++r) {
        float s = sr[r];
        s += __shfl_xor(s, 2);
        s += __shfl_xor(s, 4);
        s += __shfl_xor(s, 8);
        s += __shfl_xor(s, 16);
        if (l31 == 0) {
          int grow = m0 + wr * 128 + m * 32 + (r & 3) + 8 * (r >> 2) + 4 * hi;
          part[(size_t)grow * 32 + bx * 4 + wc] = s;
        }
      }
    }
  }
}

// logdet[row] (= or +=) sum of 32 column-group partials
__global__ void reduce_logdet(const float* __restrict__ P, float* __restrict__ logdet, int add) {
  int row = blockIdx.x * 256 + threadIdx.x;
  float s = 0.f;
#pragma unroll
  for (int g = 0; g < 32; ++g) s += P[(size_t)row * 32 + g];
  logdet[row] = add ? (logdet[row] + s) : s;
}

extern "C" void kernel_launch(void* const* d_in, const int* in_sizes, int n_in,
                              void* d_out, int out_size, void* d_ws, size_t ws_size,
                              hipStream_t stream) {
  const float* z    = (const float*)d_in[0];
  const float* cond = (const float*)d_in[1];
  const float* W1   = (const float*)d_in[4];
  const float* b1   = (const float*)d_in[5];
  const float* W2   = (const float*)d_in[6];
  const float* b2   = (const float*)d_in[7];
  const float* W3   = (const float*)d_in[8];
  const float* b3   = (const float*)d_in[9];

  float* xout   = (float*)d_out;                 // [B, D]
  float* logdet = xout + (size_t)B_ * D_;        // [B]

  // workspace (160 MiB): Wt 32 MiB | H1 64 MiB (h1 / logdet partials) |
  //                      H2 64 MiB (A0 input acts / h2)
  char* ws = (char*)d_ws;
  unsigned short* Wt = (unsigned short*)ws;
  unsigned short* H1 = (unsigned short*)(ws + 33554432);
  unsigned short* H2 = (unsigned short*)(ws + 33554432 + 67108864);
  float* Pp = (float*)H1;          // [B][32] S-partials (H1 free during GEMM3)
  unsigned short* A0 = H2;

  for (int blk = 0; blk < 2; ++blk) {
    const float* W1b = W1 + (size_t)blk * KIN_ * H_;
    const float* W2b = W2 + (size_t)blk * H_ * H_;
    const float* W3b = W3 + (size_t)blk * H_ * D_;
    const float* b1b = b1 + (size_t)blk * H_;
    const float* b2b = b2 + (size_t)blk * H_;
    const float* b3b = b3 + (size_t)blk * D_;
    // identity channels parity 1-blk; transformed channels parity blk.
    const float* xsrc = blk ? xout : z;

    // GEMM1: [B,1088] x [1088,4096]
    convT<<<dim3(H_ / 32, KIN_ / 32), 256, 0, stream>>>(W1b, Wt, KIN_, H_);
    build_act<<<dim3(5, B_), 256, 0, stream>>>(xsrc, cond, 1 - blk, A0);
    gemm8p<0><<<dim3((H_ / 256) * (B_ / 256)), 512, 0, stream>>>(
        A0, Wt, b1b, H1, nullptr, nullptr, nullptr, 0, B_, H_, KIN_);

    // GEMM2: [B,4096] x [4096,4096]
    convT<<<dim3(H_ / 32, H_ / 32), 256, 0, stream>>>(W2b, Wt, H_, H_);
    gemm8p<0><<<dim3((H_ / 256) * (B_ / 256)), 512, 0, stream>>>(
        H1, Wt, b2b, H2, nullptr, nullptr, nullptr, 0, B_, H_, H_);

    // GEMM3: [B,4096] x [4096,2048] with fused coupling epilogue
    convT<<<dim3(D_ / 32, H_ / 32), 256, 0, stream>>>(W3b, Wt, H_, D_);
    gemm8p<1><<<dim3((D_ / 256) * (B_ / 256)), 512, 0, stream>>>(
        H2, Wt, b3b, nullptr, z, xout, Pp, blk, B_, D_, H_);

    reduce_logdet<<<dim3(B_ / 256), 256, 0, stream>>>(Pp, logdet, blk);
  }
}

// Round 7
// 1034.962 us; speedup vs baseline: 1.1867x; 1.1867x over previous
//
#include <hip/hip_runtime.h>
#include <hip/hip_bf16.h>

#define B_    8192
#define D_    2048
#define H_    4096
#define C_    64
#define HALF_ 1024
#define KIN_  1088   // HALF_ + C_

typedef __attribute__((ext_vector_type(8))) short bf16x8;
typedef __attribute__((ext_vector_type(4))) float f32x4;

__device__ __forceinline__ unsigned short f2bf(float f) {
  __hip_bfloat16 h = __float2bfloat16(f);
  return *reinterpret_cast<unsigned short*>(&h);
}

__device__ __forceinline__ void gload16(const void* g, void* s) {
  __builtin_amdgcn_global_load_lds((const __attribute__((address_space(1))) void*)g,
                                   (__attribute__((address_space(3))) void*)s,
                                   16, 0, 0);
}

// W [K,N] fp32 row-major  ->  Wt [N,K] bf16 row-major (transpose + convert)
__global__ void convT(const float* __restrict__ W, unsigned short* __restrict__ Wt,
                      int K, int N) {
  __shared__ float tile[32][33];
  int tx = threadIdx.x & 31, ty = threadIdx.x >> 5;   // 32x8 threads
  int n0 = blockIdx.x * 32, k0 = blockIdx.y * 32;
#pragma unroll
  for (int i = 0; i < 4; ++i)
    tile[ty + i * 8][tx] = W[(size_t)(k0 + ty + i * 8) * N + n0 + tx];
  __syncthreads();
#pragma unroll
  for (int i = 0; i < 4; ++i)
    Wt[(size_t)(n0 + ty + i * 8) * K + k0 + tx] = f2bf(tile[tx][ty + i * 8]);
}

// A0[b, c<1024] = xsrc[b, 2c+par], A0[b, 1024:1088] = condition[b, .]  (bf16)
__global__ void build_act(const float* __restrict__ xsrc, const float* __restrict__ cond,
                          int par, unsigned short* __restrict__ A0) {
  int row = blockIdx.y;
  int col = blockIdx.x * 256 + threadIdx.x;
  if (col >= KIN_) return;
  float v;
  if (col < HALF_) {
    float2 p = ((const float2*)xsrc)[(size_t)row * (D_ / 2) + col];
    v = par ? p.y : p.x;
  } else {
    v = cond[(size_t)row * C_ + (col - HALF_)];
  }
  A0[(size_t)row * KIN_ + col] = f2bf(v);
}

// ---------------------------------------------------------------------------
// 8-phase 256x256 GEMM, BK=64, 8 waves (2Mx4N), 2-buffer 128 KiB LDS, counted
// vmcnt(6). Identical data layout/swizzle/ledger to R4 (verified: 0 bank
// conflicts, correct). Change vs R4: all blanket `lgkmcnt(0)` asm and
// sched_barrier(0) pins REMOVED from the phase machinery — compiler-generated
// ds_reads get fine-grained auto-waitcnt before each MFMA use (m97 evidence),
// which also guarantees read-completion before the post-MFMA barrier (the
// overwrite-safety condition). Only the vmcnt(6/0) asm (invisible to the
// compiler: global_load_lds -> LDS dependency) and one sched_barrier pinning
// it remain. Rationale: m141 measured order-pinning at -40%.
// MODE 0: C = bf16(relu(A*Bt^T+bias)), coalesced via per-wave LDS bounce.
// MODE 1: fused coupling epilogue (S,T interleaved; scatter + S-partials).
// ---------------------------------------------------------------------------
template <int MODE>
__global__ __launch_bounds__(512, 2)
void gemm8p(const unsigned short* __restrict__ A,
            const unsigned short* __restrict__ Bt,
            const float* __restrict__ bias,
            unsigned short* __restrict__ Cout,
            const float* __restrict__ xold, float* __restrict__ xnew,
            float* __restrict__ part, int par,
            int M, int N, int K) {
  __shared__ unsigned short lds[65536];   // 128 KiB
  char* ldsb = (char*)lds;
  const int tid = threadIdx.x;
  const int w = tid >> 6, lane = tid & 63;
  const int fr = lane & 15, fq = lane >> 4;
  const int wr = w >> 2, wc = w & 3;          // 2x4 waves, wave tile 128x64

  // XCD-aware block swizzle (nwg % 8 == 0 for all our grids)
  const int nbx = N >> 8;
  const int nwg = (int)gridDim.x;
  const int cpx = nwg >> 3;
  const int bid = (int)blockIdx.x;
  const int swz = (bid & 7) * cpx + (bid >> 3);
  const int by = swz / nbx, bx = swz - by * nbx;
  const int m0 = by << 8, n0 = bx << 8;

  // read-side swizzled base offsets: frag (m|n, kk) at base + m*1024 + kk*16384
  const int chunkp = (((fr & 1) << 2) | fq) ^ (fr >> 1);
  const int A0 = (wr * 64 + (fr >> 1)) * 128 + chunkp * 16;
  const int B0 = 32768 + (wc * 32 + (fr >> 1)) * 128 + chunkp * 16;

  // stage-side: per-slot (s=0,1) pre-swizzled global source; linear LDS dest
  int rS[2], kcolS[2];
#pragma unroll
  for (int s = 0; s < 2; ++s) {
    int q = s * 512 + w * 64 + lane;        // physical 16B chunk within slab
    int p = q >> 3, cph = q & 7;
    int clg = cph ^ (p & 7);                // logical chunk
    rS[s] = 2 * p + (clg >> 2);
    kcolS[s] = (clg & 3) * 8;
  }
  const unsigned short* sA0 = A + (size_t)(m0 + rS[0]) * K + kcolS[0];
  const unsigned short* sA1 = A + (size_t)(m0 + rS[1]) * K + kcolS[1];
  const unsigned short* sB0 = Bt + (size_t)(n0 + rS[0]) * K + kcolS[0];
  const unsigned short* sB1 = Bt + (size_t)(n0 + rS[1]) * K + kcolS[1];
  const int dst0 = w * 1024 + lane * 16;    // byte offset within slab (slot 0)

#define STAGE_A(KK, TILE, BUF) do {                                          \
    gload16(sA0 + (TILE) * 64 + (KK) * 32,                                   \
            ldsb + (BUF) + (KK) * 16384 + dst0);                             \
    gload16(sA1 + (TILE) * 64 + (KK) * 32,                                   \
            ldsb + (BUF) + (KK) * 16384 + 8192 + dst0);                      \
  } while (0)
#define STAGE_B(KK, TILE, BUF) do {                                          \
    gload16(sB0 + (TILE) * 64 + (KK) * 32,                                   \
            ldsb + (BUF) + 32768 + (KK) * 16384 + dst0);                     \
    gload16(sB1 + (TILE) * 64 + (KK) * 32,                                   \
            ldsb + (BUF) + 32768 + (KK) * 16384 + 8192 + dst0);              \
  } while (0)

  f32x4 acc[8][4];
  f32x4 z4 = {0.f, 0.f, 0.f, 0.f};
#pragma unroll
  for (int m = 0; m < 8; ++m)
#pragma unroll
    for (int n = 0; n < 4; ++n) acc[m][n] = z4;

  const int NT = K >> 6;   // BK=64; all K are multiples of 64, NT >= 3

  // prologue: tile 0 (4 HT) -> buf0; tile 1 first 3 HTs -> buf1
  STAGE_A(0, 0, 0);
  STAGE_A(1, 0, 0);
  STAGE_B(0, 0, 0);
  STAGE_B(1, 0, 0);
  STAGE_B(0, 1, 65536);
  STAGE_A(0, 1, 65536);
  STAGE_B(1, 1, 65536);
  asm volatile("s_waitcnt vmcnt(6)" ::: "memory");   // tile 0 landed; 3 HT in flight
  __builtin_amdgcn_sched_barrier(0);
  __builtin_amdgcn_s_barrier();

#define MFMA16(MB)                                                           \
    __builtin_amdgcn_s_setprio(1);                                           \
    _Pragma("unroll") for (int m = 0; m < 4; ++m)                            \
      _Pragma("unroll") for (int n = 0; n < 4; ++n)                          \
        acc[(MB) + m][n] = __builtin_amdgcn_mfma_f32_16x16x32_bf16(          \
            av[m], bv[n], acc[(MB) + m][n], 0, 0, 0);                        \
    __builtin_amdgcn_s_setprio(0);

#define TILE8(TT, S1, S234, DO_VM)                                           \
  {                                                                          \
    const int bufC = ((TT) & 1) * 65536;                                     \
    const int bufN = 65536 - bufC;                                           \
    bf16x8 av[4], bv[4];                                                     \
    /* ---- phase 1: kk0, m0-3, read B kk0 ---- */                           \
    _Pragma("unroll") for (int m = 0; m < 4; ++m)                            \
      av[m] = *(const bf16x8*)(ldsb + bufC + A0 + m * 1024);                 \
    _Pragma("unroll") for (int n = 0; n < 4; ++n)                            \
      bv[n] = *(const bf16x8*)(ldsb + bufC + B0 + n * 1024);                 \
    if (S1) { STAGE_A(1, (TT) + 1, bufN); }                                  \
    __builtin_amdgcn_s_barrier();                                            \
    MFMA16(0)                                                                \
    __builtin_amdgcn_s_barrier();                                            \
    /* ---- phase 2: kk0, m4-7, B reused ---- */                             \
    _Pragma("unroll") for (int m = 0; m < 4; ++m)                            \
      av[m] = *(const bf16x8*)(ldsb + bufC + A0 + (m + 4) * 1024);           \
    if (S234) { STAGE_B(0, (TT) + 2, bufC); }                                \
    __builtin_amdgcn_s_barrier();                                            \
    MFMA16(4)                                                                \
    __builtin_amdgcn_s_barrier();                                            \
    /* ---- phase 3: kk1, m0-3, read B kk1 ---- */                           \
    _Pragma("unroll") for (int m = 0; m < 4; ++m)                            \
      av[m] = *(const bf16x8*)(ldsb + bufC + A0 + m * 1024 + 16384);         \
    _Pragma("unroll") for (int n = 0; n < 4; ++n)                            \
      bv[n] = *(const bf16x8*)(ldsb + bufC + B0 + n * 1024 + 16384);         \
    if (S234) { STAGE_A(0, (TT) + 2, bufC); }                                \
    __builtin_amdgcn_s_barrier();                                            \
    MFMA16(0)                                                                \
    __builtin_amdgcn_s_barrier();                                            \
    /* ---- phase 4: kk1, m4-7 ---- */                                       \
    _Pragma("unroll") for (int m = 0; m < 4; ++m)                            \
      av[m] = *(const bf16x8*)(ldsb + bufC + A0 + (m + 4) * 1024 + 16384);   \
    if (S234) { STAGE_B(1, (TT) + 2, bufC); }                                \
    __builtin_amdgcn_s_barrier();                                            \
    MFMA16(4)                                                                \
    if (DO_VM == 1) asm volatile("s_waitcnt vmcnt(6)" ::: "memory");         \
    if (DO_VM == 2) asm volatile("s_waitcnt vmcnt(0)" ::: "memory");         \
    __builtin_amdgcn_sched_barrier(0);                                       \
    __builtin_amdgcn_s_barrier();                                            \
  }

  for (int T = 0; T < NT - 2; ++T) {
    TILE8(T, 1, 1, 1)
  }
  TILE8(NT - 2, 1, 0, 2)
  TILE8(NT - 1, 0, 0, 0)
#undef TILE8
#undef MFMA16
#undef STAGE_A
#undef STAGE_B

  // ---- epilogue ---- (C/D frag layout: row = fq*4 + r, col = fr; m89/m91)
  if (MODE == 0) {
    // bf16 + relu, coalesced via per-wave LDS bounce ([128 rows][128 B],
    // chunk ^= fq swizzle; <=2-way = free). K-loop ended with s_barrier.
#pragma unroll
    for (int m = 0; m < 8; ++m)
#pragma unroll
      for (int n = 0; n < 4; ++n) {
        int gcol = n0 + wc * 64 + n * 16 + fr;
        float bb = bias[gcol];
#pragma unroll
        for (int r = 0; r < 4; ++r) {
          float v = fmaxf(acc[m][n][r] + bb, 0.f);
          int lrow = m * 16 + fq * 4 + r;
          *(unsigned short*)(ldsb + w * 16384 + lrow * 128 + ((n ^ fq) * 32) + fr * 2) = f2bf(v);
        }
      }
    asm volatile("s_waitcnt lgkmcnt(0)" ::: "memory");   // own-wave region only
    __builtin_amdgcn_sched_barrier(0);
    unsigned short* Cb = Cout + (size_t)(m0 + wr * 128) * N + n0 + wc * 64;
    const int sub = lane & 7;
#pragma unroll
    for (int i = 0; i < 16; ++i) {
      int lrow = i * 8 + (lane >> 3);
      int phys = (sub >> 1) ^ ((lrow >> 2) & 3);
      bf16x8 val = *(const bf16x8*)(ldsb + w * 16384 + lrow * 128 + phys * 32 + (sub & 1) * 16);
      *(bf16x8*)(Cb + (size_t)lrow * N + sub * 8) = val;
    }
  } else {
    // fused coupling: even col 2j = S, odd = T (pair via shfl_xor 1);
    // xnew[row][2j+par] = xold[row][2j+par]*exp(S)+T; S partials -> part.
#pragma unroll
    for (int m = 0; m < 8; ++m) {
      float srow[4] = {0.f, 0.f, 0.f, 0.f};
#pragma unroll
      for (int n = 0; n < 4; ++n) {
        int gcol = n0 + wc * 64 + n * 16 + fr;
        float bb = bias[gcol];
#pragma unroll
        for (int r = 0; r < 4; ++r) {
          float v = acc[m][n][r] + bb;
          float vp = __shfl_xor(v, 1);
          if (!(fr & 1)) {
            int grow = m0 + wr * 128 + m * 16 + fq * 4 + r;
            size_t idx = (size_t)grow * N + gcol + par;
            xnew[idx] = xold[idx] * expf(v) + vp;
            srow[r] += v;
          }
        }
      }
#pragma unroll
      for (int r = 0; r < 4; ++r) {
        float s = srow[r];
        s += __shfl_xor(s, 2);
        s += __shfl_xor(s, 4);
        s += __shfl_xor(s, 8);
        if (fr == 0) {
          int grow = m0 + wr * 128 + m * 16 + fq * 4 + r;
          part[(size_t)grow * 32 + bx * 4 + wc] = s;
        }
      }
    }
  }
}

// logdet[row] (= or +=) sum of 32 column-group partials
__global__ void reduce_logdet(const float* __restrict__ P, float* __restrict__ logdet, int add) {
  int row = blockIdx.x * 256 + threadIdx.x;
  float s = 0.f;
#pragma unroll
  for (int g = 0; g < 32; ++g) s += P[(size_t)row * 32 + g];
  logdet[row] = add ? (logdet[row] + s) : s;
}

extern "C" void kernel_launch(void* const* d_in, const int* in_sizes, int n_in,
                              void* d_out, int out_size, void* d_ws, size_t ws_size,
                              hipStream_t stream) {
  const float* z    = (const float*)d_in[0];
  const float* cond = (const float*)d_in[1];
  const float* W1   = (const float*)d_in[4];
  const float* b1   = (const float*)d_in[5];
  const float* W2   = (const float*)d_in[6];
  const float* b2   = (const float*)d_in[7];
  const float* W3   = (const float*)d_in[8];
  const float* b3   = (const float*)d_in[9];

  float* xout   = (float*)d_out;                 // [B, D]
  float* logdet = xout + (size_t)B_ * D_;        // [B]

  // workspace (160 MiB): Wt 32 MiB | H1 64 MiB (h1 / logdet partials) |
  //                      H2 64 MiB (A0 input acts / h2)
  char* ws = (char*)d_ws;
  unsigned short* Wt = (unsigned short*)ws;
  unsigned short* H1 = (unsigned short*)(ws + 33554432);
  unsigned short* H2 = (unsigned short*)(ws + 33554432 + 67108864);
  float* Pp = (float*)H1;          // [B][32] S-partials (H1 free during GEMM3)
  unsigned short* A0 = H2;

  for (int blk = 0; blk < 2; ++blk) {
    const float* W1b = W1 + (size_t)blk * KIN_ * H_;
    const float* W2b = W2 + (size_t)blk * H_ * H_;
    const float* W3b = W3 + (size_t)blk * H_ * D_;
    const float* b1b = b1 + (size_t)blk * H_;
    const float* b2b = b2 + (size_t)blk * H_;
    const float* b3b = b3 + (size_t)blk * D_;
    // identity channels parity 1-blk; transformed channels parity blk.
    const float* xsrc = blk ? xout : z;

    // GEMM1: [B,1088] x [1088,4096]
    convT<<<dim3(H_ / 32, KIN_ / 32), 256, 0, stream>>>(W1b, Wt, KIN_, H_);
    build_act<<<dim3(5, B_), 256, 0, stream>>>(xsrc, cond, 1 - blk, A0);
    gemm8p<0><<<dim3((H_ / 256) * (B_ / 256)), 512, 0, stream>>>(
        A0, Wt, b1b, H1, nullptr, nullptr, nullptr, 0, B_, H_, KIN_);

    // GEMM2: [B,4096] x [4096,4096]
    convT<<<dim3(H_ / 32, H_ / 32), 256, 0, stream>>>(W2b, Wt, H_, H_);
    gemm8p<0><<<dim3((H_ / 256) * (B_ / 256)), 512, 0, stream>>>(
        H1, Wt, b2b, H2, nullptr, nullptr, nullptr, 0, B_, H_, H_);

    // GEMM3: [B,4096] x [4096,2048] with fused coupling epilogue
    convT<<<dim3(D_ / 32, H_ / 32), 256, 0, stream>>>(W3b, Wt, H_, D_);
    gemm8p<1><<<dim3((D_ / 256) * (B_ / 256)), 512, 0, stream>>>(
        H2, Wt, b3b, nullptr, z, xout, Pp, blk, B_, D_, H_);

    reduce_logdet<<<dim3(B_ / 256), 256, 0, stream>>>(Pp, logdet, blk);
  }
}

// Round 8
// 1024.381 us; speedup vs baseline: 1.1990x; 1.0103x over previous
//
#include <hip/hip_runtime.h>
#include <hip/hip_bf16.h>

#define B_    8192
#define D_    2048
#define H_    4096
#define C_    64
#define HALF_ 1024
#define KIN_  1088   // HALF_ + C_

typedef __attribute__((ext_vector_type(8))) short bf16x8;
typedef __attribute__((ext_vector_type(4))) float f32x4;

__device__ __forceinline__ unsigned short f2bf(float f) {
  __hip_bfloat16 h = __float2bfloat16(f);
  return *reinterpret_cast<unsigned short*>(&h);
}

__device__ __forceinline__ void gload16(const void* g, void* s) {
  __builtin_amdgcn_global_load_lds((const __attribute__((address_space(1))) void*)g,
                                   (__attribute__((address_space(3))) void*)s,
                                   16, 0, 0);
}

// W [K,N] fp32 row-major  ->  Wt [N,K] bf16 row-major (transpose + convert)
__global__ void convT(const float* __restrict__ W, unsigned short* __restrict__ Wt,
                      int K, int N) {
  __shared__ float tile[32][33];
  int tx = threadIdx.x & 31, ty = threadIdx.x >> 5;   // 32x8 threads
  int n0 = blockIdx.x * 32, k0 = blockIdx.y * 32;
#pragma unroll
  for (int i = 0; i < 4; ++i)
    tile[ty + i * 8][tx] = W[(size_t)(k0 + ty + i * 8) * N + n0 + tx];
  __syncthreads();
#pragma unroll
  for (int i = 0; i < 4; ++i)
    Wt[(size_t)(n0 + ty + i * 8) * K + k0 + tx] = f2bf(tile[tx][ty + i * 8]);
}

// A0[b, c<1024] = xsrc[b, 2c+par], A0[b, 1024:1088] = condition[b, .]  (bf16)
__global__ void build_act(const float* __restrict__ xsrc, const float* __restrict__ cond,
                          int par, unsigned short* __restrict__ A0) {
  int row = blockIdx.y;
  int col = blockIdx.x * 256 + threadIdx.x;
  if (col >= KIN_) return;
  float v;
  if (col < HALF_) {
    float2 p = ((const float2*)xsrc)[(size_t)row * (D_ / 2) + col];
    v = par ? p.y : p.x;
  } else {
    v = cond[(size_t)row * C_ + (col - HALF_)];
  }
  A0[(size_t)row * KIN_ + col] = f2bf(v);
}

// ---------------------------------------------------------------------------
// 256x256 GEMM, BK=64, 8 waves (2Mx4N), 2-buffer 128 KiB LDS, counted
// vmcnt(6). Layout/swizzle/staging/ledger identical to R4/R7 (verified: 0
// bank conflicts). R8 change: PIPE OVERLAP — each phase's ds_reads are issued
// ONE PHASE EARLY (register double-buffer), so the LDS pipe (2260 cyc/K-tile
// per CU) runs concurrently with the MFMA pipe (2483 cyc) instead of
// serializing (R7 measured 4775 cyc/K-tile = sum). Pre-MFMA barriers dropped:
// 4 barriers/K-tile {B1,B2,B3,B4}. Overwrite-safety ledger (re-proven):
//   stage into region R is issued only after a barrier that follows (in all
//   waves) the MFMAs consuming R's reads -> reads completed. Tile-entry data
//   guarantee unchanged: vmcnt(6)+B4 rendezvous (each wave drains its own
//   stage loads; B4 makes it collective).
// sched_barrier(0) after each read cluster pins the prefetch (prevents the
// compiler sinking reads to their use point).
// MODE 0: C = bf16(relu(A*Bt^T+bias)), coalesced via per-wave LDS bounce.
// MODE 1: fused coupling epilogue (S,T interleaved; scatter + S-partials).
// ---------------------------------------------------------------------------
template <int MODE>
__global__ __launch_bounds__(512, 2)
void gemm8p(const unsigned short* __restrict__ A,
            const unsigned short* __restrict__ Bt,
            const float* __restrict__ bias,
            unsigned short* __restrict__ Cout,
            const float* __restrict__ xold, float* __restrict__ xnew,
            float* __restrict__ part, int par,
            int M, int N, int K) {
  __shared__ unsigned short lds[65536];   // 128 KiB
  char* ldsb = (char*)lds;
  const int tid = threadIdx.x;
  const int w = tid >> 6, lane = tid & 63;
  const int fr = lane & 15, fq = lane >> 4;
  const int wr = w >> 2, wc = w & 3;          // 2x4 waves, wave tile 128x64

  // XCD-aware block swizzle (nwg % 8 == 0 for all our grids)
  const int nbx = N >> 8;
  const int nwg = (int)gridDim.x;
  const int cpx = nwg >> 3;
  const int bid = (int)blockIdx.x;
  const int swz = (bid & 7) * cpx + (bid >> 3);
  const int by = swz / nbx, bx = swz - by * nbx;
  const int m0 = by << 8, n0 = bx << 8;

  // read-side swizzled base offsets: frag (m|n, kk) at base + m*1024 + kk*16384
  const int chunkp = (((fr & 1) << 2) | fq) ^ (fr >> 1);
  const int A0 = (wr * 64 + (fr >> 1)) * 128 + chunkp * 16;
  const int B0 = 32768 + (wc * 32 + (fr >> 1)) * 128 + chunkp * 16;

  // stage-side: per-slot (s=0,1) pre-swizzled global source; linear LDS dest
  int rS[2], kcolS[2];
#pragma unroll
  for (int s = 0; s < 2; ++s) {
    int q = s * 512 + w * 64 + lane;        // physical 16B chunk within slab
    int p = q >> 3, cph = q & 7;
    int clg = cph ^ (p & 7);                // logical chunk
    rS[s] = 2 * p + (clg >> 2);
    kcolS[s] = (clg & 3) * 8;
  }
  const unsigned short* sA0 = A + (size_t)(m0 + rS[0]) * K + kcolS[0];
  const unsigned short* sA1 = A + (size_t)(m0 + rS[1]) * K + kcolS[1];
  const unsigned short* sB0 = Bt + (size_t)(n0 + rS[0]) * K + kcolS[0];
  const unsigned short* sB1 = Bt + (size_t)(n0 + rS[1]) * K + kcolS[1];
  const int dst0 = w * 1024 + lane * 16;    // byte offset within slab (slot 0)

#define STAGE_A(KK, TILE, BUF) do {                                          \
    gload16(sA0 + (TILE) * 64 + (KK) * 32,                                   \
            ldsb + (BUF) + (KK) * 16384 + dst0);                             \
    gload16(sA1 + (TILE) * 64 + (KK) * 32,                                   \
            ldsb + (BUF) + (KK) * 16384 + 8192 + dst0);                      \
  } while (0)
#define STAGE_B(KK, TILE, BUF) do {                                          \
    gload16(sB0 + (TILE) * 64 + (KK) * 32,                                   \
            ldsb + (BUF) + 32768 + (KK) * 16384 + dst0);                     \
    gload16(sB1 + (TILE) * 64 + (KK) * 32,                                   \
            ldsb + (BUF) + 32768 + (KK) * 16384 + 8192 + dst0);              \
  } while (0)

  f32x4 acc[8][4];
  f32x4 z4 = {0.f, 0.f, 0.f, 0.f};
#pragma unroll
  for (int m = 0; m < 8; ++m)
#pragma unroll
    for (int n = 0; n < 4; ++n) acc[m][n] = z4;

  const int NT = K >> 6;   // BK=64; all K are multiples of 64, NT >= 3

  // prologue: tile 0 (4 HT) -> buf0; tile 1 first 3 HTs -> buf1
  STAGE_A(0, 0, 0);
  STAGE_A(1, 0, 0);
  STAGE_B(0, 0, 0);
  STAGE_B(1, 0, 0);
  STAGE_B(0, 1, 65536);
  STAGE_A(0, 1, 65536);
  STAGE_B(1, 1, 65536);
  asm volatile("s_waitcnt vmcnt(6)" ::: "memory");   // tile 0 landed; 3 HT in flight
  __builtin_amdgcn_sched_barrier(0);
  __builtin_amdgcn_s_barrier();

#define MFMA16(MB, AV, BV)                                                   \
    __builtin_amdgcn_s_setprio(1);                                           \
    _Pragma("unroll") for (int m = 0; m < 4; ++m)                            \
      _Pragma("unroll") for (int n = 0; n < 4; ++n)                          \
        acc[(MB) + m][n] = __builtin_amdgcn_mfma_f32_16x16x32_bf16(          \
            AV[m], BV[n], acc[(MB) + m][n], 0, 0, 0);                        \
    __builtin_amdgcn_s_setprio(0);

#define TILE8(TT, S1, S234, DO_VM)                                           \
  {                                                                          \
    const int bufC = ((TT) & 1) * 65536;                                     \
    const int bufN = 65536 - bufC;                                           \
    bf16x8 bv0[4], a00[4], a01[4], bv1[4], a10[4], a11[4];                   \
    /* reads kk0 (feed ph1+ph2) */                                           \
    _Pragma("unroll") for (int n = 0; n < 4; ++n)                            \
      bv0[n] = *(const bf16x8*)(ldsb + bufC + B0 + n * 1024);                \
    _Pragma("unroll") for (int m = 0; m < 4; ++m)                            \
      a00[m] = *(const bf16x8*)(ldsb + bufC + A0 + m * 1024);                \
    _Pragma("unroll") for (int m = 0; m < 4; ++m)                            \
      a01[m] = *(const bf16x8*)(ldsb + bufC + A0 + (m + 4) * 1024);          \
    __builtin_amdgcn_sched_barrier(0);                                       \
    if (S1) { STAGE_A(1, (TT) + 1, bufN); }                                  \
    /* ph1 MFMA overlaps the a01 reads still in flight */                    \
    MFMA16(0, a00, bv0)                                                      \
    __builtin_amdgcn_s_barrier();  /* B1: bv0/a00 consumed by all waves */   \
    /* reads kk1 part 1 (feed ph3) — overlap ph2 MFMA */                     \
    _Pragma("unroll") for (int n = 0; n < 4; ++n)                            \
      bv1[n] = *(const bf16x8*)(ldsb + bufC + B0 + n * 1024 + 16384);        \
    _Pragma("unroll") for (int m = 0; m < 4; ++m)                            \
      a10[m] = *(const bf16x8*)(ldsb + bufC + A0 + m * 1024 + 16384);        \
    __builtin_amdgcn_sched_barrier(0);                                       \
    if (S234) { STAGE_B(0, (TT) + 2, bufC); }                                \
    MFMA16(4, a01, bv0)                                                      \
    __builtin_amdgcn_s_barrier();  /* B2: a01 consumed */                    \
    /* reads kk1 part 2 (feed ph4) — overlap ph3 MFMA */                     \
    _Pragma("unroll") for (int m = 0; m < 4; ++m)                            \
      a11[m] = *(const bf16x8*)(ldsb + bufC + A0 + (m + 4) * 1024 + 16384);  \
    __builtin_amdgcn_sched_barrier(0);                                       \
    if (S234) { STAGE_A(0, (TT) + 2, bufC); }                                \
    MFMA16(0, a10, bv1)                                                      \
    __builtin_amdgcn_s_barrier();  /* B3: bv1/a10 consumed */                \
    if (S234) { STAGE_B(1, (TT) + 2, bufC); }                                \
    MFMA16(4, a11, bv1)                                                      \
    if (DO_VM == 1) asm volatile("s_waitcnt vmcnt(6)" ::: "memory");         \
    if (DO_VM == 2) asm volatile("s_waitcnt vmcnt(0)" ::: "memory");         \
    __builtin_amdgcn_sched_barrier(0);                                       \
    __builtin_amdgcn_s_barrier();  /* B4: tile rendezvous (vmcnt collective) */ \
  }

  for (int T = 0; T < NT - 2; ++T) {
    TILE8(T, 1, 1, 1)
  }
  TILE8(NT - 2, 1, 0, 2)
  TILE8(NT - 1, 0, 0, 0)
#undef TILE8
#undef MFMA16
#undef STAGE_A
#undef STAGE_B

  // ---- epilogue ---- (C/D frag layout: row = fq*4 + r, col = fr; m89/m91)
  if (MODE == 0) {
    // bf16 + relu, coalesced via per-wave LDS bounce ([128 rows][128 B],
    // chunk ^= fq swizzle; <=2-way = free). K-loop ended with s_barrier.
#pragma unroll
    for (int m = 0; m < 8; ++m)
#pragma unroll
      for (int n = 0; n < 4; ++n) {
        int gcol = n0 + wc * 64 + n * 16 + fr;
        float bb = bias[gcol];
#pragma unroll
        for (int r = 0; r < 4; ++r) {
          float v = fmaxf(acc[m][n][r] + bb, 0.f);
          int lrow = m * 16 + fq * 4 + r;
          *(unsigned short*)(ldsb + w * 16384 + lrow * 128 + ((n ^ fq) * 32) + fr * 2) = f2bf(v);
        }
      }
    asm volatile("s_waitcnt lgkmcnt(0)" ::: "memory");   // own-wave region only
    __builtin_amdgcn_sched_barrier(0);
    unsigned short* Cb = Cout + (size_t)(m0 + wr * 128) * N + n0 + wc * 64;
    const int sub = lane & 7;
#pragma unroll
    for (int i = 0; i < 16; ++i) {
      int lrow = i * 8 + (lane >> 3);
      int phys = (sub >> 1) ^ ((lrow >> 2) & 3);
      bf16x8 val = *(const bf16x8*)(ldsb + w * 16384 + lrow * 128 + phys * 32 + (sub & 1) * 16);
      *(bf16x8*)(Cb + (size_t)lrow * N + sub * 8) = val;
    }
  } else {
    // fused coupling: even col 2j = S, odd = T (pair via shfl_xor 1);
    // xnew[row][2j+par] = xold[row][2j+par]*exp(S)+T; S partials -> part.
#pragma unroll
    for (int m = 0; m < 8; ++m) {
      float srow[4] = {0.f, 0.f, 0.f, 0.f};
#pragma unroll
      for (int n = 0; n < 4; ++n) {
        int gcol = n0 + wc * 64 + n * 16 + fr;
        float bb = bias[gcol];
#pragma unroll
        for (int r = 0; r < 4; ++r) {
          float v = acc[m][n][r] + bb;
          float vp = __shfl_xor(v, 1);
          if (!(fr & 1)) {
            int grow = m0 + wr * 128 + m * 16 + fq * 4 + r;
            size_t idx = (size_t)grow * N + gcol + par;
            xnew[idx] = xold[idx] * expf(v) + vp;
            srow[r] += v;
          }
        }
      }
#pragma unroll
      for (int r = 0; r < 4; ++r) {
        float s = srow[r];
        s += __shfl_xor(s, 2);
        s += __shfl_xor(s, 4);
        s += __shfl_xor(s, 8);
        if (fr == 0) {
          int grow = m0 + wr * 128 + m * 16 + fq * 4 + r;
          part[(size_t)grow * 32 + bx * 4 + wc] = s;
        }
      }
    }
  }
}

// logdet[row] (= or +=) sum of 32 column-group partials
__global__ void reduce_logdet(const float* __restrict__ P, float* __restrict__ logdet, int add) {
  int row = blockIdx.x * 256 + threadIdx.x;
  float s = 0.f;
#pragma unroll
  for (int g = 0; g < 32; ++g) s += P[(size_t)row * 32 + g];
  logdet[row] = add ? (logdet[row] + s) : s;
}

extern "C" void kernel_launch(void* const* d_in, const int* in_sizes, int n_in,
                              void* d_out, int out_size, void* d_ws, size_t ws_size,
                              hipStream_t stream) {
  const float* z    = (const float*)d_in[0];
  const float* cond = (const float*)d_in[1];
  const float* W1   = (const float*)d_in[4];
  const float* b1   = (const float*)d_in[5];
  const float* W2   = (const float*)d_in[6];
  const float* b2   = (const float*)d_in[7];
  const float* W3   = (const float*)d_in[8];
  const float* b3   = (const float*)d_in[9];

  float* xout   = (float*)d_out;                 // [B, D]
  float* logdet = xout + (size_t)B_ * D_;        // [B]

  // workspace (160 MiB): Wt 32 MiB | H1 64 MiB (h1 / logdet partials) |
  //                      H2 64 MiB (A0 input acts / h2)
  char* ws = (char*)d_ws;
  unsigned short* Wt = (unsigned short*)ws;
  unsigned short* H1 = (unsigned short*)(ws + 33554432);
  unsigned short* H2 = (unsigned short*)(ws + 33554432 + 67108864);
  float* Pp = (float*)H1;          // [B][32] S-partials (H1 free during GEMM3)
  unsigned short* A0 = H2;

  for (int blk = 0; blk < 2; ++blk) {
    const float* W1b = W1 + (size_t)blk * KIN_ * H_;
    const float* W2b = W2 + (size_t)blk * H_ * H_;
    const float* W3b = W3 + (size_t)blk * H_ * D_;
    const float* b1b = b1 + (size_t)blk * H_;
    const float* b2b = b2 + (size_t)blk * H_;
    const float* b3b = b3 + (size_t)blk * D_;
    // identity channels parity 1-blk; transformed channels parity blk.
    const float* xsrc = blk ? xout : z;

    // GEMM1: [B,1088] x [1088,4096]
    convT<<<dim3(H_ / 32, KIN_ / 32), 256, 0, stream>>>(W1b, Wt, KIN_, H_);
    build_act<<<dim3(5, B_), 256, 0, stream>>>(xsrc, cond, 1 - blk, A0);
    gemm8p<0><<<dim3((H_ / 256) * (B_ / 256)), 512, 0, stream>>>(
        A0, Wt, b1b, H1, nullptr, nullptr, nullptr, 0, B_, H_, KIN_);

    // GEMM2: [B,4096] x [4096,4096]
    convT<<<dim3(H_ / 32, H_ / 32), 256, 0, stream>>>(W2b, Wt, H_, H_);
    gemm8p<0><<<dim3((H_ / 256) * (B_ / 256)), 512, 0, stream>>>(
        H1, Wt, b2b, H2, nullptr, nullptr, nullptr, 0, B_, H_, H_);

    // GEMM3: [B,4096] x [4096,2048] with fused coupling epilogue
    convT<<<dim3(D_ / 32, H_ / 32), 256, 0, stream>>>(W3b, Wt, H_, D_);
    gemm8p<1><<<dim3((D_ / 256) * (B_ / 256)), 512, 0, stream>>>(
        H2, Wt, b3b, nullptr, z, xout, Pp, blk, B_, D_, H_);

    reduce_logdet<<<dim3(B_ / 256), 256, 0, stream>>>(Pp, logdet, blk);
  }
}

// Round 9
// 1021.670 us; speedup vs baseline: 1.2022x; 1.0027x over previous
//
#include <hip/hip_runtime.h>
#include <hip/hip_bf16.h>

#define B_    8192
#define D_    2048
#define H_    4096
#define C_    64
#define HALF_ 1024
#define KIN_  1088   // HALF_ + C_

typedef __attribute__((ext_vector_type(8))) short bf16x8;
typedef __attribute__((ext_vector_type(4))) float f32x4;

__device__ __forceinline__ unsigned short f2bf(float f) {
  __hip_bfloat16 h = __float2bfloat16(f);
  return *reinterpret_cast<unsigned short*>(&h);
}

__device__ __forceinline__ void gload16(const void* g, void* s) {
  __builtin_amdgcn_global_load_lds((const __attribute__((address_space(1))) void*)g,
                                   (__attribute__((address_space(3))) void*)s,
                                   16, 0, 0);
}

// W [K,N] fp32 row-major  ->  Wt [N,K] bf16 row-major (transpose + convert)
__global__ void convT(const float* __restrict__ W, unsigned short* __restrict__ Wt,
                      int K, int N) {
  __shared__ float tile[32][33];
  int tx = threadIdx.x & 31, ty = threadIdx.x >> 5;   // 32x8 threads
  int n0 = blockIdx.x * 32, k0 = blockIdx.y * 32;
#pragma unroll
  for (int i = 0; i < 4; ++i)
    tile[ty + i * 8][tx] = W[(size_t)(k0 + ty + i * 8) * N + n0 + tx];
  __syncthreads();
#pragma unroll
  for (int i = 0; i < 4; ++i)
    Wt[(size_t)(n0 + ty + i * 8) * K + k0 + tx] = f2bf(tile[tx][ty + i * 8]);
}

// A0[b, c<1024] = xsrc[b, 2c+par], A0[b, 1024:1088] = condition[b, .]  (bf16)
__global__ void build_act(const float* __restrict__ xsrc, const float* __restrict__ cond,
                          int par, unsigned short* __restrict__ A0) {
  int row = blockIdx.y;
  int col = blockIdx.x * 256 + threadIdx.x;
  if (col >= KIN_) return;
  float v;
  if (col < HALF_) {
    float2 p = ((const float2*)xsrc)[(size_t)row * (D_ / 2) + col];
    v = par ? p.y : p.x;
  } else {
    v = cond[(size_t)row * C_ + (col - HALF_)];
  }
  A0[(size_t)row * KIN_ + col] = f2bf(v);
}

// ---------------------------------------------------------------------------
// 256x256 GEMM, BK=32, 8 waves (2Mx4N), 3-buffer 96 KiB LDS ring, ONE barrier
// + ONE counted vmcnt per K-step. Slab layout/swizzle identical to R4/R7/R8
// (verified 0 bank conflicts): buffer = A slab 16KB + B slab 16KB; slab =
// [128 lines][128B], line p = rows 2p,2p+1; logical 16B chunk c =
// ((row&1)<<2)|k-octet, physical = c ^ (p&7); staging = linear LDS dest +
// inverse-swizzled per-lane global source.
//
// Window T (steady state):
//   stage tile T+2 -> buf[(T+2)%3]   (4 gload_lds; target holds T-1, whose
//                                     frag reads completed >=2 barriers ago)
//   s_waitcnt vmcnt(4)               (outstanding = T+1:4 + T+2:4 -> drains
//                                     T+1; per-wave confirm BEFORE barrier)
//   s_barrier                        (T+1 now collectively visible)
//   read frags(T+1) from buf[(T+1)%3]  (12 ds_read_b128 -> ping-pong reg set)
//   MFMA x32 on frags(T)             (read last window; compiler lgkmcnt(12)
//                                     lets the new reads run under the MFMAs)
// Tail: window NT-2 uses vmcnt(0); window NT-1 computes only.
// MODE 0: C = bf16(relu(.+bias)) via per-wave LDS bounce (full 128KB avail
// post-loop). MODE 1: fused coupling epilogue.
// ---------------------------------------------------------------------------
template <int MODE>
__global__ __launch_bounds__(512, 2)
void gemm8p(const unsigned short* __restrict__ A,
            const unsigned short* __restrict__ Bt,
            const float* __restrict__ bias,
            unsigned short* __restrict__ Cout,
            const float* __restrict__ xold, float* __restrict__ xnew,
            float* __restrict__ part, int par,
            int M, int N, int K) {
  __shared__ unsigned short lds[65536];   // 128 KiB declared; ring uses 96 KiB
  char* ldsb = (char*)lds;
  const int tid = threadIdx.x;
  const int w = tid >> 6, lane = tid & 63;
  const int fr = lane & 15, fq = lane >> 4;
  const int wr = w >> 2, wc = w & 3;          // 2x4 waves, wave tile 128x64

  // XCD-aware block swizzle (nwg % 8 == 0 for all our grids)
  const int nbx = N >> 8;
  const int nwg = (int)gridDim.x;
  const int cpx = nwg >> 3;
  const int bid = (int)blockIdx.x;
  const int swz = (bid & 7) * cpx + (bid >> 3);
  const int by = swz / nbx, bx = swz - by * nbx;
  const int m0 = by << 8, n0 = bx << 8;

  // read-side swizzled base offsets within a buffer (A slab @0, B slab @16384)
  const int chunkp = (((fr & 1) << 2) | fq) ^ (fr >> 1);
  const int A0 = (wr * 64 + (fr >> 1)) * 128 + chunkp * 16;
  const int B0 = 16384 + (wc * 32 + (fr >> 1)) * 128 + chunkp * 16;

  // stage-side: per-slot (s=0,1) pre-swizzled global source; linear LDS dest
  int rS[2], kcolS[2];
#pragma unroll
  for (int s = 0; s < 2; ++s) {
    int q = s * 512 + w * 64 + lane;        // physical 16B chunk within slab
    int p = q >> 3, cph = q & 7;
    int clg = cph ^ (p & 7);                // logical chunk
    rS[s] = 2 * p + (clg >> 2);
    kcolS[s] = (clg & 3) * 8;
  }
  const unsigned short* sA0 = A + (size_t)(m0 + rS[0]) * K + kcolS[0];
  const unsigned short* sA1 = A + (size_t)(m0 + rS[1]) * K + kcolS[1];
  const unsigned short* sB0 = Bt + (size_t)(n0 + rS[0]) * K + kcolS[0];
  const unsigned short* sB1 = Bt + (size_t)(n0 + rS[1]) * K + kcolS[1];
  const int dst0 = w * 1024 + lane * 16;    // byte offset within slab (slot 0)

// stage one full BK=32 tile (A 16KB + B 16KB) into buffer at OFF; advance ptrs
#define STAGE_ALL(OFF) do {                                                  \
    gload16(sA0, ldsb + (OFF) + dst0);                                       \
    gload16(sA1, ldsb + (OFF) + 8192 + dst0);                                \
    gload16(sB0, ldsb + (OFF) + 16384 + dst0);                               \
    gload16(sB1, ldsb + (OFF) + 24576 + dst0);                               \
    sA0 += 32; sA1 += 32; sB0 += 32; sB1 += 32;                              \
  } while (0)

#define RDFRAGS(AV, BV, OFF)                                                 \
    _Pragma("unroll") for (int n = 0; n < 4; ++n)                            \
      BV[n] = *(const bf16x8*)(ldsb + (OFF) + B0 + n * 1024);                \
    _Pragma("unroll") for (int m = 0; m < 8; ++m)                            \
      AV[m] = *(const bf16x8*)(ldsb + (OFF) + A0 + m * 1024);

#define MFMA32(AV, BV)                                                       \
    __builtin_amdgcn_s_setprio(1);                                           \
    _Pragma("unroll") for (int m = 0; m < 8; ++m)                            \
      _Pragma("unroll") for (int n = 0; n < 4; ++n)                          \
        acc[m][n] = __builtin_amdgcn_mfma_f32_16x16x32_bf16(                 \
            AV[m], BV[n], acc[m][n], 0, 0, 0);                               \
    __builtin_amdgcn_s_setprio(0);

// window: stage T+2 -> stg; counted vmcnt; barrier; read frags(T+1) from nxt;
// MFMA tile T; rotate ring.
#define WIN(STG, VM, RD, AVr, BVr, AVm, BVm)                                 \
  {                                                                          \
    if (STG) STAGE_ALL(stg);                                                 \
    if (VM == 1) asm volatile("s_waitcnt vmcnt(4)" ::: "memory");            \
    if (VM == 2) asm volatile("s_waitcnt vmcnt(0)" ::: "memory");            \
    __builtin_amdgcn_sched_barrier(0);                                       \
    __builtin_amdgcn_s_barrier();                                            \
    if (RD) { RDFRAGS(AVr, BVr, nxt) }                                       \
    MFMA32(AVm, BVm)                                                         \
    int _t = cur; cur = nxt; nxt = stg; stg = _t;                            \
  }

  f32x4 acc[8][4];
  f32x4 z4 = {0.f, 0.f, 0.f, 0.f};
#pragma unroll
  for (int m = 0; m < 8; ++m)
#pragma unroll
    for (int n = 0; n < 4; ++n) acc[m][n] = z4;

  const int NT = K >> 5;   // BK=32; all K multiples of 64 -> NT even, >= 4

  bf16x8 av0[8], bv0[4], av1[8], bv1[4];

  // prologue: stage tiles 0,1; confirm tile 0; read its frags into set0
  STAGE_ALL(0);
  STAGE_ALL(32768);
  asm volatile("s_waitcnt vmcnt(4)" ::: "memory");
  __builtin_amdgcn_sched_barrier(0);
  __builtin_amdgcn_s_barrier();
  RDFRAGS(av0, bv0, 0)
  int cur = 0, nxt = 32768, stg = 65536;

  for (int P = 0; P < (NT - 2) / 2; ++P) {
    WIN(1, 1, 1, av1, bv1, av0, bv0)   // even window: compute set0, read set1
    WIN(1, 1, 1, av0, bv0, av1, bv1)   // odd window: compute set1, read set0
  }
  WIN(0, 2, 1, av1, bv1, av0, bv0)     // window NT-2: drain, read tile NT-1
  WIN(0, 0, 0, av1, bv1, av1, bv1)     // window NT-1: compute only
  __builtin_amdgcn_s_barrier();        // all lgkm drained per-wave before this
#undef WIN
#undef MFMA32
#undef RDFRAGS
#undef STAGE_ALL

  // ---- epilogue ---- (C/D frag layout: row = fq*4 + r, col = fr; m89/m91)
  if (MODE == 0) {
    // bf16 + relu, coalesced via per-wave LDS bounce ([128 rows][128 B],
    // chunk ^= fq swizzle; <=2-way = free). Full 128KB LDS free post-loop.
#pragma unroll
    for (int m = 0; m < 8; ++m)
#pragma unroll
      for (int n = 0; n < 4; ++n) {
        int gcol = n0 + wc * 64 + n * 16 + fr;
        float bb = bias[gcol];
#pragma unroll
        for (int r = 0; r < 4; ++r) {
          float v = fmaxf(acc[m][n][r] + bb, 0.f);
          int lrow = m * 16 + fq * 4 + r;
          *(unsigned short*)(ldsb + w * 16384 + lrow * 128 + ((n ^ fq) * 32) + fr * 2) = f2bf(v);
        }
      }
    asm volatile("s_waitcnt lgkmcnt(0)" ::: "memory");   // own-wave region only
    __builtin_amdgcn_sched_barrier(0);
    unsigned short* Cb = Cout + (size_t)(m0 + wr * 128) * N + n0 + wc * 64;
    const int sub = lane & 7;
#pragma unroll
    for (int i = 0; i < 16; ++i) {
      int lrow = i * 8 + (lane >> 3);
      int phys = (sub >> 1) ^ ((lrow >> 2) & 3);
      bf16x8 val = *(const bf16x8*)(ldsb + w * 16384 + lrow * 128 + phys * 32 + (sub & 1) * 16);
      *(bf16x8*)(Cb + (size_t)lrow * N + sub * 8) = val;
    }
  } else {
    // fused coupling: even col 2j = S, odd = T (pair via shfl_xor 1);
    // xnew[row][2j+par] = xold[row][2j+par]*exp(S)+T; S partials -> part.
#pragma unroll
    for (int m = 0; m < 8; ++m) {
      float srow[4] = {0.f, 0.f, 0.f, 0.f};
#pragma unroll
      for (int n = 0; n < 4; ++n) {
        int gcol = n0 + wc * 64 + n * 16 + fr;
        float bb = bias[gcol];
#pragma unroll
        for (int r = 0; r < 4; ++r) {
          float v = acc[m][n][r] + bb;
          float vp = __shfl_xor(v, 1);
          if (!(fr & 1)) {
            int grow = m0 + wr * 128 + m * 16 + fq * 4 + r;
            size_t idx = (size_t)grow * N + gcol + par;
            xnew[idx] = xold[idx] * expf(v) + vp;
            srow[r] += v;
          }
        }
      }
#pragma unroll
      for (int r = 0; r < 4; ++r) {
        float s = srow[r];
        s += __shfl_xor(s, 2);
        s += __shfl_xor(s, 4);
        s += __shfl_xor(s, 8);
        if (fr == 0) {
          int grow = m0 + wr * 128 + m * 16 + fq * 4 + r;
          part[(size_t)grow * 32 + bx * 4 + wc] = s;
        }
      }
    }
  }
}

// logdet[row] (= or +=) sum of 32 column-group partials
__global__ void reduce_logdet(const float* __restrict__ P, float* __restrict__ logdet, int add) {
  int row = blockIdx.x * 256 + threadIdx.x;
  float s = 0.f;
#pragma unroll
  for (int g = 0; g < 32; ++g) s += P[(size_t)row * 32 + g];
  logdet[row] = add ? (logdet[row] + s) : s;
}

extern "C" void kernel_launch(void* const* d_in, const int* in_sizes, int n_in,
                              void* d_out, int out_size, void* d_ws, size_t ws_size,
                              hipStream_t stream) {
  const float* z    = (const float*)d_in[0];
  const float* cond = (const float*)d_in[1];
  const float* W1   = (const float*)d_in[4];
  const float* b1   = (const float*)d_in[5];
  const float* W2   = (const float*)d_in[6];
  const float* b2   = (const float*)d_in[7];
  const float* W3   = (const float*)d_in[8];
  const float* b3   = (const float*)d_in[9];

  float* xout   = (float*)d_out;                 // [B, D]
  float* logdet = xout + (size_t)B_ * D_;        // [B]

  // workspace (160 MiB): Wt 32 MiB | H1 64 MiB (h1 / logdet partials) |
  //                      H2 64 MiB (A0 input acts / h2)
  char* ws = (char*)d_ws;
  unsigned short* Wt = (unsigned short*)ws;
  unsigned short* H1 = (unsigned short*)(ws + 33554432);
  unsigned short* H2 = (unsigned short*)(ws + 33554432 + 67108864);
  float* Pp = (float*)H1;          // [B][32] S-partials (H1 free during GEMM3)
  unsigned short* A0 = H2;

  for (int blk = 0; blk < 2; ++blk) {
    const float* W1b = W1 + (size_t)blk * KIN_ * H_;
    const float* W2b = W2 + (size_t)blk * H_ * H_;
    const float* W3b = W3 + (size_t)blk * H_ * D_;
    const float* b1b = b1 + (size_t)blk * H_;
    const float* b2b = b2 + (size_t)blk * H_;
    const float* b3b = b3 + (size_t)blk * D_;
    // identity channels parity 1-blk; transformed channels parity blk.
    const float* xsrc = blk ? xout : z;

    // GEMM1: [B,1088] x [1088,4096]
    convT<<<dim3(H_ / 32, KIN_ / 32), 256, 0, stream>>>(W1b, Wt, KIN_, H_);
    build_act<<<dim3(5, B_), 256, 0, stream>>>(xsrc, cond, 1 - blk, A0);
    gemm8p<0><<<dim3((H_ / 256) * (B_ / 256)), 512, 0, stream>>>(
        A0, Wt, b1b, H1, nullptr, nullptr, nullptr, 0, B_, H_, KIN_);

    // GEMM2: [B,4096] x [4096,4096]
    convT<<<dim3(H_ / 32, H_ / 32), 256, 0, stream>>>(W2b, Wt, H_, H_);
    gemm8p<0><<<dim3((H_ / 256) * (B_ / 256)), 512, 0, stream>>>(
        H1, Wt, b2b, H2, nullptr, nullptr, nullptr, 0, B_, H_, H_);

    // GEMM3: [B,4096] x [4096,2048] with fused coupling epilogue
    convT<<<dim3(D_ / 32, H_ / 32), 256, 0, stream>>>(W3b, Wt, H_, D_);
    gemm8p<1><<<dim3((D_ / 256) * (B_ / 256)), 512, 0, stream>>>(
        H2, Wt, b3b, nullptr, z, xout, Pp, blk, B_, D_, H_);

    reduce_logdet<<<dim3(B_ / 256), 256, 0, stream>>>(Pp, logdet, blk);
  }
}